// Round 7
// baseline (118.793 us; speedup 1.0000x reference)
//
#include <hip/hip_runtime.h>
#include <math.h>

#define NSTUFF 6
#define NCLS   10          // N_STUFF + N_THING
#define NBOX   32
#define NTHING 4
#define RR     28
#define HH     768
#define WW     704
#define NPIX   (HH * WW)   // 540672
#define BB     2
#define LL     (1 + NSTUFF + NBOX)   // 39
#define NEGV   (-100.0f)

#define TW 64
#define TH 8
#define TILES_X (WW / TW)            // 11
#define TILES_Y (HH / TH)            // 96
#define NTILES  (TILES_X * TILES_Y)  // 2112 per batch
#define NHIST   (NBOX * NCLS + NSTUFF)

__device__ __forceinline__ float sigmoidf_(float x) {
    return 1.0f / (1.0f + expf(-x));
}

// ---------------------------------------------------------------------------
// K1: tiled fused logits + argmax + histograms. 128-thread blocks on 64x8
// tiles (4 px/thread via float4 -> 16B/lane coalescing) give 4224 blocks x
// 2 waves = 8448 waves = ~100% occupancy (vs 52% at 256-thread/64x16 —
// k_fuse is latency-bound, so resident-wave count is the lever).
// Per-tile box cull in-register by wave 0. Winner (0..37) stored as uchar4.
// Sequential-argmax semantics preserved via the gap rule (skipped boxes
// contribute exactly -0.0f; only the first box of a skipped run can win, and
// only while bv < 0).
// ---------------------------------------------------------------------------
__global__ __launch_bounds__(128) void k_fuse(
    const float* __restrict__ sem,   // [B][10][H][W]
    const float* __restrict__ roi,   // [B][32][4][28][28]
    const float* __restrict__ bbx,   // [B][32][4]
    const int*   __restrict__ cls,   // [B][32]
    uchar4*      __restrict__ pred8, // ws region, [B][H][W] bytes as uchar4
    int*         __restrict__ counts,
    int*         __restrict__ stuffh)
{
    const int b = blockIdx.y;
    __shared__ int   sh_y0[NBOX], sh_x0[NBOX], sh_yme[NBOX], sh_xme[NBOX];
    __shared__ int   sh_yie[NBOX], sh_xie[NBOX], sh_moff[NBOX], sh_cls[NBOX];
    __shared__ float sh_y0f[NBOX], sh_x0f[NBOX], sh_sy[NBOX], sh_sx[NBOX];
    __shared__ int   sh_list[NBOX];
    __shared__ int   sh_nbox;
    __shared__ int   sh_cnt[NHIST];

    const int t = threadIdx.x;
    const int tile = blockIdx.x;
    const int tx0 = (tile % TILES_X) * TW;
    const int ty0 = (tile / TILES_X) * TH;

    const int xq = tx0 + (t & 15) * 4;      // first of this thread's 4 pixels
    const int y  = ty0 + (t >> 4);          // rows 0..7
    const int p  = y * WW + xq;

    // All 10 channels upfront as float4 (independent loads, one latency round)
    const float* semb = sem + (size_t)b * NCLS * NPIX;
    float4 s4[NCLS];
    #pragma unroll
    for (int c = 0; c < NCLS; ++c)
        s4[c] = *(const float4*)(semb + (size_t)c * NPIX + p);

    for (int i = t; i < NHIST; i += 128) sh_cnt[i] = 0;

    // wave 0: per-box setup + in-register tile cull
    if (t < 64) {
        bool flag = false;
        if (t < NBOX) {
            const float* bbp = bbx + ((size_t)b * NBOX + t) * 4;
            float y0f = bbp[0], x0f = bbp[1], y1f = bbp[2], x1f = bbp[3];
            int y0 = (int)floorf(y0f), x0 = (int)floorf(x0f);
            int y1 = (int)floorf(y1f), x1 = (int)floorf(x1f);
            int yme = min(y1 + 1, HH), xme = min(x1 + 1, WW);
            int yie = (int)rintf(y1f) + 1, xie = (int)rintf(x1f) + 1;
            sh_y0[t] = y0;  sh_x0[t] = x0;
            sh_yme[t] = yme; sh_xme[t] = xme;
            sh_yie[t] = yie; sh_xie[t] = xie;
            sh_y0f[t] = (float)y0; sh_x0f[t] = (float)x0;
            float hh = (float)max(y1 - y0 + 1, 1);
            float ww = (float)max(x1 - x0 + 1, 1);
            sh_sy[t] = 28.0f / hh;  sh_sx[t] = 28.0f / ww;
            int c = cls[b * NBOX + t];
            sh_cls[t] = c;
            sh_moff[t] = (((b * NBOX + t) * NTHING) + c) * (RR * RR);
            int uy = max(yme, yie), ux = max(xme, xie);
            flag = (y0 < ty0 + TH) && (uy > ty0) && (x0 < tx0 + TW) && (ux > tx0);
        }
        unsigned long long m = __ballot(flag);
        if (flag) {
            int pos = __popcll(m & (((unsigned long long)1 << t) - 1ull));
            sh_list[pos] = t;
        }
        if (t == 0) sh_nbox = __popcll(m);
    }
    __syncthreads();

    const int nb = sh_nbox;

    auto doPix = [&](const float* s, int y_, int x_, int& bi_o, int& sp_o) {
        const float yf = (float)y_, xf = (float)x_;
        // sem_pred: full 10-channel argmax, first-occurrence ties
        float sb = s[0]; int sp = 0;
        #pragma unroll
        for (int c = 1; c < NCLS; ++c) if (s[c] > sb) { sb = s[c]; sp = c; }

        // stuff argmax
        float bv = s[0]; int bi = 0;
        #pragma unroll
        for (int c = 1; c < NSTUFF; ++c) if (s[c] > bv) { bv = s[c]; bi = c; }

        int prev = -1;
        for (int j = 0; j < nb; ++j) {
            const int n = sh_list[j];
            if (n > prev + 1 && bv < 0.0f) { bv = -0.0f; bi = NSTUFF + prev + 1; }
            const bool in_m = (y_ >= max(sh_y0[n], 0)) & (y_ < sh_yme[n]) &
                              (x_ >= max(sh_x0[n], 0)) & (x_ < sh_xme[n]);
            const bool in_i = (y_ >= sh_y0[n]) & (y_ < sh_yie[n]) &
                              (x_ >= sh_x0[n]) & (x_ < sh_xie[n]);
            float v;
            if (in_m | in_i) {
                float pm = NEGV;
                if (in_m) {
                    float sy = __fsub_rn(__fmul_rn(__fadd_rn(__fsub_rn(yf, sh_y0f[n]), 0.5f), sh_sy[n]), 0.5f);
                    sy = fminf(fmaxf(sy, 0.0f), 27.0f);
                    int ylo = (int)sy;
                    int yhi = min(ylo + 1, RR - 1);
                    float wy = __fsub_rn(sy, (float)ylo);
                    float sx = __fsub_rn(__fmul_rn(__fadd_rn(__fsub_rn(xf, sh_x0f[n]), 0.5f), sh_sx[n]), 0.5f);
                    sx = fminf(fmaxf(sx, 0.0f), 27.0f);
                    int xlo = (int)sx;
                    int xhi = min(xlo + 1, RR - 1);
                    float wx = __fsub_rn(sx, (float)xlo);
                    const float* m = roi + sh_moff[n];
                    float m00 = m[ylo * RR + xlo], m01 = m[ylo * RR + xhi];
                    float m10 = m[yhi * RR + xlo], m11 = m[yhi * RR + xhi];
                    float omy = __fsub_rn(1.0f, wy), omx = __fsub_rn(1.0f, wx);
                    float rl = __fadd_rn(__fmul_rn(m00, omy), __fmul_rn(m10, wy));
                    float rh = __fadd_rn(__fmul_rn(m01, omy), __fmul_rn(m11, wy));
                    pm = __fadd_rn(__fmul_rn(rl, omx), __fmul_rn(rh, wx));
                }
                float pi = NEGV;
                if (in_i) {
                    int c = sh_cls[n];
                    pi = (c == 0) ? s[6] : (c == 1) ? s[7] : (c == 2) ? s[8] : s[9];
                }
                v = __fmul_rn(__fadd_rn(sigmoidf_(pi), sigmoidf_(pm)), __fadd_rn(pi, pm));
            } else {
                v = -0.0f;
            }
            if (v > bv) { bv = v; bi = NSTUFF + n; }
            prev = n;
        }
        if (prev < NBOX - 1 && bv < 0.0f) { bi = NSTUFF + prev + 1; }
        bi_o = bi; sp_o = sp;
    };

    int bis[4], sps[4];
    #pragma unroll
    for (int j = 0; j < 4; ++j) {
        float s[NCLS];
        #pragma unroll
        for (int c = 0; c < NCLS; ++c) s[c] = ((const float*)&s4[c])[j];
        doPix(s, y, xq + j, bis[j], sps[j]);
    }

    uchar4 pv;
    pv.x = (unsigned char)bis[0]; pv.y = (unsigned char)bis[1];
    pv.z = (unsigned char)bis[2]; pv.w = (unsigned char)bis[3];
    pred8[((size_t)b * NPIX + p) >> 2] = pv;

    // histogram: ballot-aggregate stuff bins; scatter-atomic instance pixels
    const int lane = t & 63;
    #pragma unroll
    for (int s = 0; s < NSTUFF; ++s) {
        int c = 0;
        #pragma unroll
        for (int j = 0; j < 4; ++j) c += __popcll(__ballot(bis[j] == s));
        if (lane == 0 && c) atomicAdd(&sh_cnt[NBOX * NCLS + s], c);
    }
    #pragma unroll
    for (int j = 0; j < 4; ++j)
        if (bis[j] >= NSTUFF) atomicAdd(&sh_cnt[(bis[j] - NSTUFF) * NCLS + sps[j]], 1);

    __syncthreads();
    for (int i = t; i < NHIST; i += 128) {
        int v = sh_cnt[i];
        if (v) {
            if (i < NBOX * NCLS) atomicAdd(&counts[b * NBOX * NCLS + i], v);
            else                 atomicAdd(&stuffh[b * NSTUFF + (i - NBOX * NCLS)], v);
        }
    }
}

// ---------------------------------------------------------------------------
// K2: fused label + seam remap. 128-thread blocks (8448 waves -> full
// occupancy). Pred bytes loaded BEFORE the LUT barrier so wave-0's LUT
// recompute latency hides behind the global load. Ranks are pure functions
// of ballot masks. Block (0,b) also writes po_cls / po_iscrowd.
// ---------------------------------------------------------------------------
__global__ __launch_bounds__(128) void k_relabel(
    const int*    __restrict__ counts,
    const int*    __restrict__ stuffh,
    const int*    __restrict__ cls,
    const uchar4* __restrict__ pred8,
    int*          __restrict__ out)
{
    const int b = blockIdx.y;
    const int t = threadIdx.x;
    __shared__ int slut[NSTUFF + NBOX];
    __shared__ int l_sh[NSTUFF];
    __shared__ int l_ih[NBOX];
    __shared__ int l_isem[NBOX];
    __shared__ int l_co[LL];

    // issue the pred load first (independent of the LUT)
    const size_t q = (size_t)b * (NPIX / 4) + (size_t)blockIdx.x * 128 + t;
    const uchar4 v = pred8[q];

    int  ssum = 0, mj = 0, semv = 0, idx = -1;
    bool pres = false, ts = false;

    if (t < 64) {
        if (t < NSTUFF) l_sh[t] = stuffh[b * NSTUFF + t];
        if (t < NBOX)  { l_ih[t] = 0; l_isem[t] = 255; }
        if (t < LL)      l_co[t] = 255;

        if (t < NBOX) {
            const int* C = counts + ((size_t)b * NBOX + t) * NCLS;
            int c[NCLS];
            #pragma unroll
            for (int i = 0; i < NCLS; ++i) c[i] = C[i];
            int m = c[0]; mj = 0; ssum = c[0];
            #pragma unroll
            for (int i = 1; i < NCLS; ++i) {
                ssum += c[i];
                if (c[i] > m) { m = c[i]; mj = i; }
            }
            pres = ssum > 0;
            int thing = cls[b * NBOX + t] + NSTUFF;
            ts = pres && (mj != thing) && (2 * m >= ssum) && (mj < NSTUFF);
            semv = ts ? mj : thing;
        }
        unsigned long long pm = __ballot(pres);
        idx = __popcll(pm & (((unsigned long long)2 << t) - 1ull)) - 1;

        if (t < NBOX && pres &&  ts) atomicAdd(&l_sh[mj], ssum);
        if (t < NBOX && pres && !ts) { atomicAdd(&l_ih[idx], ssum); l_isem[idx] = semv; }
    }
    __syncthreads();

    if (t < 64) {
        bool spres = (t < NSTUFF) && (l_sh[t] > 0);
        unsigned long long sm = __ballot(spres);
        const int nst = __popcll(sm);
        bool ipres = (t < NBOX) && (l_ih[t] > 0);
        unsigned long long im = __ballot(ipres);

        auto srank = [&](int c) { return __popcll(sm & (((unsigned long long)2 << c) - 1ull)) - 1; };
        auto irank = [&](int j) { return __popcll(im & (((unsigned long long)2 << j) - 1ull)) - 1; };

        if (t < NSTUFF) slut[t] = 1 + srank(t);
        if (t < NBOX) {
            int q2 = idx < 0 ? 0 : idx;
            slut[NSTUFF + t] = ts ? (1 + srank(mj)) : (1 + nst + irank(q2));
        }
        if (spres) l_co[1 + srank(t)] = t;
        if (ipres) l_co[1 + nst + irank(t)] = l_isem[t];
    }
    __syncthreads();

    int4 o;
    o.x = slut[v.x];
    o.y = slut[v.y];
    o.z = slut[v.z];
    o.w = slut[v.w];
    ((int4*)out)[q] = o;

    if (blockIdx.x == 0 && t < LL) {
        int* ocls = out + (size_t)BB * NPIX + b * LL;
        int* ocrd = out + (size_t)BB * NPIX + BB * LL + b * LL;
        ocls[t] = l_co[t];
        ocrd[t] = 0;
    }
}

extern "C" void kernel_launch(void* const* d_in, const int* in_sizes, int n_in,
                              void* d_out, int out_size, void* d_ws, size_t ws_size,
                              hipStream_t stream) {
    (void)in_sizes; (void)n_in; (void)out_size; (void)ws_size;
    const float* sem = (const float*)d_in[0];
    const float* roi = (const float*)d_in[1];
    const float* bbx = (const float*)d_in[2];
    const int*   cls = (const int*)d_in[3];
    int* out = (int*)d_out;

    int* counts = (int*)d_ws;                        // [B][32][10]
    int* stuffh = counts + BB * NBOX * NCLS;         // [B][6]
    // 652 ints = 2608 B (16B-aligned); pred bytes follow
    uchar4* pred8 = (uchar4*)(stuffh + BB * NSTUFF); // [B*NPIX] bytes

    hipMemsetAsync(d_ws, 0, (BB * NBOX * NCLS + BB * NSTUFF) * sizeof(int), stream);

    dim3 g1(NTILES, BB);
    k_fuse<<<g1, 128, 0, stream>>>(sem, roi, bbx, cls, pred8, counts, stuffh);
    dim3 g2(NPIX / 512, BB);   // 1056 blocks/batch, 128 thr x 4 px
    k_relabel<<<g2, 128, 0, stream>>>(counts, stuffh, cls, pred8, out);
}

// Round 8
// 109.278 us; speedup vs baseline: 1.0871x; 1.0871x over previous
//
#include <hip/hip_runtime.h>
#include <math.h>

#define NSTUFF 6
#define NCLS   10          // N_STUFF + N_THING
#define NBOX   32
#define NTHING 4
#define RR     28
#define HH     768
#define WW     704
#define NPIX   (HH * WW)   // 540672
#define BB     2
#define LL     (1 + NSTUFF + NBOX)   // 39
#define NEGV   (-100.0f)

// Tile choice (measured): 64x16 / 256 thr / 4 px-thread float4 = 1056 blocks,
// 52% occupancy -> 109.6 us end-to-end (R6). Doubling block count for 100%
// occupancy (R7: 64x8 / 128 thr, 4224 blocks) REGRESSED to 118.8 us —
// per-block fixed cost (setup+cull+hist flush+barriers) dominates over
// occupancy for this latency-profile. Keep 64x16/256.
#define TW 64
#define TH 16
#define TILES_X (WW / TW)            // 11
#define TILES_Y (HH / TH)            // 48
#define NTILES  (TILES_X * TILES_Y)  // 528 per batch
#define NHIST   (NBOX * NCLS + NSTUFF)

__device__ __forceinline__ float sigmoidf_(float x) {
    return 1.0f / (1.0f + expf(-x));
}

// ---------------------------------------------------------------------------
// K1: tiled fused logits + argmax + histograms. 4 px/thread via float4 sem
// loads (all 10 channels upfront -> one latency round). Per-tile box cull
// in-register by wave 0. Winner index (0..37) stored as uchar4 into ws.
// Sequential-argmax semantics preserved via the gap rule (skipped boxes
// contribute exactly -0.0f; only the first box of a skipped run can win, and
// only while bv < 0).
// ---------------------------------------------------------------------------
__global__ __launch_bounds__(256) void k_fuse(
    const float* __restrict__ sem,   // [B][10][H][W]
    const float* __restrict__ roi,   // [B][32][4][28][28]
    const float* __restrict__ bbx,   // [B][32][4]
    const int*   __restrict__ cls,   // [B][32]
    uchar4*      __restrict__ pred8, // ws region, [B][H][W] bytes as uchar4
    int*         __restrict__ counts,
    int*         __restrict__ stuffh)
{
    const int b = blockIdx.y;
    __shared__ int   sh_y0[NBOX], sh_x0[NBOX], sh_yme[NBOX], sh_xme[NBOX];
    __shared__ int   sh_yie[NBOX], sh_xie[NBOX], sh_moff[NBOX], sh_cls[NBOX];
    __shared__ float sh_y0f[NBOX], sh_x0f[NBOX], sh_sy[NBOX], sh_sx[NBOX];
    __shared__ int   sh_list[NBOX];
    __shared__ int   sh_nbox;
    __shared__ int   sh_cnt[NHIST];

    const int t = threadIdx.x;
    const int tile = blockIdx.x;
    const int tx0 = (tile % TILES_X) * TW;
    const int ty0 = (tile / TILES_X) * TH;

    const int xq = tx0 + (t & 15) * 4;      // first of this thread's 4 pixels
    const int y  = ty0 + (t >> 4);
    const int p  = y * WW + xq;

    // All 10 channels upfront as float4 (independent loads, one latency round)
    const float* semb = sem + (size_t)b * NCLS * NPIX;
    float4 s4[NCLS];
    #pragma unroll
    for (int c = 0; c < NCLS; ++c)
        s4[c] = *(const float4*)(semb + (size_t)c * NPIX + p);

    for (int i = t; i < NHIST; i += 256) sh_cnt[i] = 0;

    // wave 0: per-box setup + in-register tile cull
    if (t < 64) {
        bool flag = false;
        if (t < NBOX) {
            const float* bbp = bbx + ((size_t)b * NBOX + t) * 4;
            float y0f = bbp[0], x0f = bbp[1], y1f = bbp[2], x1f = bbp[3];
            int y0 = (int)floorf(y0f), x0 = (int)floorf(x0f);
            int y1 = (int)floorf(y1f), x1 = (int)floorf(x1f);
            int yme = min(y1 + 1, HH), xme = min(x1 + 1, WW);
            int yie = (int)rintf(y1f) + 1, xie = (int)rintf(x1f) + 1;
            sh_y0[t] = y0;  sh_x0[t] = x0;
            sh_yme[t] = yme; sh_xme[t] = xme;
            sh_yie[t] = yie; sh_xie[t] = xie;
            sh_y0f[t] = (float)y0; sh_x0f[t] = (float)x0;
            float hh = (float)max(y1 - y0 + 1, 1);
            float ww = (float)max(x1 - x0 + 1, 1);
            sh_sy[t] = 28.0f / hh;  sh_sx[t] = 28.0f / ww;
            int c = cls[b * NBOX + t];
            sh_cls[t] = c;
            sh_moff[t] = (((b * NBOX + t) * NTHING) + c) * (RR * RR);
            int uy = max(yme, yie), ux = max(xme, xie);
            flag = (y0 < ty0 + TH) && (uy > ty0) && (x0 < tx0 + TW) && (ux > tx0);
        }
        unsigned long long m = __ballot(flag);
        if (flag) {
            int pos = __popcll(m & (((unsigned long long)1 << t) - 1ull));
            sh_list[pos] = t;
        }
        if (t == 0) sh_nbox = __popcll(m);
    }
    __syncthreads();

    const int nb = sh_nbox;

    auto doPix = [&](const float* s, int y_, int x_, int& bi_o, int& sp_o) {
        const float yf = (float)y_, xf = (float)x_;
        // sem_pred: full 10-channel argmax, first-occurrence ties
        float sb = s[0]; int sp = 0;
        #pragma unroll
        for (int c = 1; c < NCLS; ++c) if (s[c] > sb) { sb = s[c]; sp = c; }

        // stuff argmax
        float bv = s[0]; int bi = 0;
        #pragma unroll
        for (int c = 1; c < NSTUFF; ++c) if (s[c] > bv) { bv = s[c]; bi = c; }

        int prev = -1;
        for (int j = 0; j < nb; ++j) {
            const int n = sh_list[j];
            if (n > prev + 1 && bv < 0.0f) { bv = -0.0f; bi = NSTUFF + prev + 1; }
            const bool in_m = (y_ >= max(sh_y0[n], 0)) & (y_ < sh_yme[n]) &
                              (x_ >= max(sh_x0[n], 0)) & (x_ < sh_xme[n]);
            const bool in_i = (y_ >= sh_y0[n]) & (y_ < sh_yie[n]) &
                              (x_ >= sh_x0[n]) & (x_ < sh_xie[n]);
            float v;
            if (in_m | in_i) {
                float pm = NEGV;
                if (in_m) {
                    float sy = __fsub_rn(__fmul_rn(__fadd_rn(__fsub_rn(yf, sh_y0f[n]), 0.5f), sh_sy[n]), 0.5f);
                    sy = fminf(fmaxf(sy, 0.0f), 27.0f);
                    int ylo = (int)sy;
                    int yhi = min(ylo + 1, RR - 1);
                    float wy = __fsub_rn(sy, (float)ylo);
                    float sx = __fsub_rn(__fmul_rn(__fadd_rn(__fsub_rn(xf, sh_x0f[n]), 0.5f), sh_sx[n]), 0.5f);
                    sx = fminf(fmaxf(sx, 0.0f), 27.0f);
                    int xlo = (int)sx;
                    int xhi = min(xlo + 1, RR - 1);
                    float wx = __fsub_rn(sx, (float)xlo);
                    const float* m = roi + sh_moff[n];
                    float m00 = m[ylo * RR + xlo], m01 = m[ylo * RR + xhi];
                    float m10 = m[yhi * RR + xlo], m11 = m[yhi * RR + xhi];
                    float omy = __fsub_rn(1.0f, wy), omx = __fsub_rn(1.0f, wx);
                    float rl = __fadd_rn(__fmul_rn(m00, omy), __fmul_rn(m10, wy));
                    float rh = __fadd_rn(__fmul_rn(m01, omy), __fmul_rn(m11, wy));
                    pm = __fadd_rn(__fmul_rn(rl, omx), __fmul_rn(rh, wx));
                }
                float pi = NEGV;
                if (in_i) {
                    int c = sh_cls[n];
                    pi = (c == 0) ? s[6] : (c == 1) ? s[7] : (c == 2) ? s[8] : s[9];
                }
                v = __fmul_rn(__fadd_rn(sigmoidf_(pi), sigmoidf_(pm)), __fadd_rn(pi, pm));
            } else {
                v = -0.0f;
            }
            if (v > bv) { bv = v; bi = NSTUFF + n; }
            prev = n;
        }
        if (prev < NBOX - 1 && bv < 0.0f) { bi = NSTUFF + prev + 1; }
        bi_o = bi; sp_o = sp;
    };

    int bis[4], sps[4];
    #pragma unroll
    for (int j = 0; j < 4; ++j) {
        float s[NCLS];
        #pragma unroll
        for (int c = 0; c < NCLS; ++c) s[c] = ((const float*)&s4[c])[j];
        doPix(s, y, xq + j, bis[j], sps[j]);
    }

    uchar4 pv;
    pv.x = (unsigned char)bis[0]; pv.y = (unsigned char)bis[1];
    pv.z = (unsigned char)bis[2]; pv.w = (unsigned char)bis[3];
    pred8[((size_t)b * NPIX + p) >> 2] = pv;

    // histogram: ballot-aggregate stuff bins; scatter-atomic instance pixels
    const int lane = t & 63;
    #pragma unroll
    for (int s = 0; s < NSTUFF; ++s) {
        int c = 0;
        #pragma unroll
        for (int j = 0; j < 4; ++j) c += __popcll(__ballot(bis[j] == s));
        if (lane == 0 && c) atomicAdd(&sh_cnt[NBOX * NCLS + s], c);
    }
    #pragma unroll
    for (int j = 0; j < 4; ++j)
        if (bis[j] >= NSTUFF) atomicAdd(&sh_cnt[(bis[j] - NSTUFF) * NCLS + sps[j]], 1);

    __syncthreads();
    for (int i = t; i < NHIST; i += 256) {
        int v = sh_cnt[i];
        if (v) {
            if (i < NBOX * NCLS) atomicAdd(&counts[b * NBOX * NCLS + i], v);
            else                 atomicAdd(&stuffh[b * NSTUFF + (i - NBOX * NCLS)], v);
        }
    }
}

// ---------------------------------------------------------------------------
// K2: fused label + seam remap. Pred bytes are loaded BEFORE the LUT barrier
// (independent of it) so wave-0's LUT recompute latency is hidden behind the
// global load. Ranks are pure functions of ballot masks. Block (0,b) also
// writes po_cls / po_iscrowd.
// ---------------------------------------------------------------------------
__global__ __launch_bounds__(256) void k_relabel(
    const int*    __restrict__ counts,
    const int*    __restrict__ stuffh,
    const int*    __restrict__ cls,
    const uchar4* __restrict__ pred8,
    int*          __restrict__ out)
{
    const int b = blockIdx.y;
    const int t = threadIdx.x;
    __shared__ int slut[NSTUFF + NBOX];
    __shared__ int l_sh[NSTUFF];
    __shared__ int l_ih[NBOX];
    __shared__ int l_isem[NBOX];
    __shared__ int l_co[LL];

    // issue the pred load first (independent of the LUT)
    const size_t q = (size_t)b * (NPIX / 4) + (size_t)blockIdx.x * 256 + t;
    const uchar4 v = pred8[q];

    int  ssum = 0, mj = 0, semv = 0, idx = -1;
    bool pres = false, ts = false;

    if (t < 64) {
        if (t < NSTUFF) l_sh[t] = stuffh[b * NSTUFF + t];
        if (t < NBOX)  { l_ih[t] = 0; l_isem[t] = 255; }
        if (t < LL)      l_co[t] = 255;

        if (t < NBOX) {
            const int* C = counts + ((size_t)b * NBOX + t) * NCLS;
            int c[NCLS];
            #pragma unroll
            for (int i = 0; i < NCLS; ++i) c[i] = C[i];
            int m = c[0]; mj = 0; ssum = c[0];
            #pragma unroll
            for (int i = 1; i < NCLS; ++i) {
                ssum += c[i];
                if (c[i] > m) { m = c[i]; mj = i; }
            }
            pres = ssum > 0;
            int thing = cls[b * NBOX + t] + NSTUFF;
            ts = pres && (mj != thing) && (2 * m >= ssum) && (mj < NSTUFF);
            semv = ts ? mj : thing;
        }
        unsigned long long pm = __ballot(pres);
        idx = __popcll(pm & (((unsigned long long)2 << t) - 1ull)) - 1;

        if (t < NBOX && pres &&  ts) atomicAdd(&l_sh[mj], ssum);
        if (t < NBOX && pres && !ts) { atomicAdd(&l_ih[idx], ssum); l_isem[idx] = semv; }
    }
    __syncthreads();

    if (t < 64) {
        bool spres = (t < NSTUFF) && (l_sh[t] > 0);
        unsigned long long sm = __ballot(spres);
        const int nst = __popcll(sm);
        bool ipres = (t < NBOX) && (l_ih[t] > 0);
        unsigned long long im = __ballot(ipres);

        auto srank = [&](int c) { return __popcll(sm & (((unsigned long long)2 << c) - 1ull)) - 1; };
        auto irank = [&](int j) { return __popcll(im & (((unsigned long long)2 << j) - 1ull)) - 1; };

        if (t < NSTUFF) slut[t] = 1 + srank(t);
        if (t < NBOX) {
            int q2 = idx < 0 ? 0 : idx;
            slut[NSTUFF + t] = ts ? (1 + srank(mj)) : (1 + nst + irank(q2));
        }
        if (spres) l_co[1 + srank(t)] = t;
        if (ipres) l_co[1 + nst + irank(t)] = l_isem[t];
    }
    __syncthreads();

    int4 o;
    o.x = slut[v.x];
    o.y = slut[v.y];
    o.z = slut[v.z];
    o.w = slut[v.w];
    ((int4*)out)[q] = o;

    if (blockIdx.x == 0 && t < LL) {
        int* ocls = out + (size_t)BB * NPIX + b * LL;
        int* ocrd = out + (size_t)BB * NPIX + BB * LL + b * LL;
        ocls[t] = l_co[t];
        ocrd[t] = 0;
    }
}

extern "C" void kernel_launch(void* const* d_in, const int* in_sizes, int n_in,
                              void* d_out, int out_size, void* d_ws, size_t ws_size,
                              hipStream_t stream) {
    (void)in_sizes; (void)n_in; (void)out_size; (void)ws_size;
    const float* sem = (const float*)d_in[0];
    const float* roi = (const float*)d_in[1];
    const float* bbx = (const float*)d_in[2];
    const int*   cls = (const int*)d_in[3];
    int* out = (int*)d_out;

    int* counts = (int*)d_ws;                        // [B][32][10]
    int* stuffh = counts + BB * NBOX * NCLS;         // [B][6]
    // 652 ints = 2608 B (16B-aligned); pred bytes follow
    uchar4* pred8 = (uchar4*)(stuffh + BB * NSTUFF); // [B*NPIX] bytes

    hipMemsetAsync(d_ws, 0, (BB * NBOX * NCLS + BB * NSTUFF) * sizeof(int), stream);

    dim3 g1(NTILES, BB);
    k_fuse<<<g1, 256, 0, stream>>>(sem, roi, bbx, cls, pred8, counts, stuffh);
    dim3 g2(NPIX / 1024, BB);   // 528 blocks/batch, 256 thr x 4 px
    k_relabel<<<g2, 256, 0, stream>>>(counts, stuffh, cls, pred8, out);
}